// Round 1
// baseline (123.877 us; speedup 1.0000x reference)
//
#include <hip/hip_runtime.h>
#include <hip/hip_bf16.h>
#include <float.h>

// RandomAugment: out = concat(p, where(dist(s, p) > 1, s, 0))
//   s = u * (max(p) - min(p)) + min(p)
//   dist[m] = sqrt(clip(min_n ||s_m - p_n||^2, 0))  via  s2 + pn2 - 2 s.p
//
// Key restructure: min_n fl(s2 + x_n) == fl(s2 + min_n x_n)  (monotone rounding),
// so the inner loop is a 3-fma chain + fmin = 4 VALU ops/pair.

constexpr int CHUNKS = 8;   // waves per block, each handles N/CHUNKS points

__global__ __launch_bounds__(256) void prep_kernel(
    const float* __restrict__ p, int N,
    float* __restrict__ out, float4* __restrict__ P4, float* __restrict__ mmx) {
  const int tid = threadIdx.x;
  if (blockIdx.x == 0) {
    // block 0: min/max over the N points (3 components each)
    float mn0 = FLT_MAX, mn1 = FLT_MAX, mn2 = FLT_MAX;
    float mx0 = -FLT_MAX, mx1 = -FLT_MAX, mx2 = -FLT_MAX;
    for (int j = tid; j < N; j += 256) {
      float x = p[3 * j], y = p[3 * j + 1], z = p[3 * j + 2];
      mn0 = fminf(mn0, x); mx0 = fmaxf(mx0, x);
      mn1 = fminf(mn1, y); mx1 = fmaxf(mx1, y);
      mn2 = fminf(mn2, z); mx2 = fmaxf(mx2, z);
    }
    // wave (64-lane) butterfly reduce
    for (int off = 32; off; off >>= 1) {
      mn0 = fminf(mn0, __shfl_xor(mn0, off));
      mn1 = fminf(mn1, __shfl_xor(mn1, off));
      mn2 = fminf(mn2, __shfl_xor(mn2, off));
      mx0 = fmaxf(mx0, __shfl_xor(mx0, off));
      mx1 = fmaxf(mx1, __shfl_xor(mx1, off));
      mx2 = fmaxf(mx2, __shfl_xor(mx2, off));
    }
    __shared__ float smn[4][3], smx[4][3];
    const int w = tid >> 6;
    if ((tid & 63) == 0) {
      smn[w][0] = mn0; smn[w][1] = mn1; smn[w][2] = mn2;
      smx[w][0] = mx0; smx[w][1] = mx1; smx[w][2] = mx2;
    }
    __syncthreads();
    if (tid == 0) {
      for (int k = 0; k < 3; ++k) {
        float a = smn[0][k], b = smx[0][k];
        for (int w2 = 1; w2 < 4; ++w2) {
          a = fminf(a, smn[w2][k]);
          b = fmaxf(b, smx[w2][k]);
        }
        mmx[k] = a;       // mm
        mmx[3 + k] = b;   // mx
      }
    }
  } else {
    // blocks 1..: copy p -> out[0:3N] and build P4 = {x, y, z, x^2+y^2+z^2}
    const int stride = (gridDim.x - 1) * 256;
    for (int j = (blockIdx.x - 1) * 256 + tid; j < N; j += stride) {
      float x = p[3 * j], y = p[3 * j + 1], z = p[3 * j + 2];
      out[3 * j] = x; out[3 * j + 1] = y; out[3 * j + 2] = z;
      float n2 = __fadd_rn(__fadd_rn(__fmul_rn(x, x), __fmul_rn(y, y)),
                           __fmul_rn(z, z));
      P4[j] = make_float4(x, y, z, n2);
    }
  }
}

__global__ __launch_bounds__(64 * CHUNKS) void dist_kernel(
    const float* __restrict__ u, int M, int N,
    const float4* __restrict__ P4, const float* __restrict__ mmx,
    float* __restrict__ out) {
  const int lane = threadIdx.x;        // 0..63  -> sample within block
  const int wv = threadIdx.y;          // 0..CHUNKS-1 -> point chunk
  const int samp = blockIdx.x * 64 + lane;

  const float mm0 = mmx[0], mm1 = mmx[1], mm2 = mmx[2];
  const float r0 = __fsub_rn(mmx[3], mm0);
  const float r1 = __fsub_rn(mmx[4], mm1);
  const float r2 = __fsub_rn(mmx[5], mm2);

  float sx = 0.0f, sy = 0.0f, sz = 0.0f;
  if (samp < M) {
    // bit-exact with numpy's u*(mx-mm)+mm (mul then add, no contraction)
    sx = __fadd_rn(__fmul_rn(u[3 * samp], r0), mm0);
    sy = __fadd_rn(__fmul_rn(u[3 * samp + 1], r1), mm1);
    sz = __fadd_rn(__fmul_rn(u[3 * samp + 2], r2), mm2);
  }
  const float m2x = -2.0f * sx, m2y = -2.0f * sy, m2z = -2.0f * sz;

  const int cnt = (N + CHUNKS - 1) / CHUNKS;
  const int beg = wv * cnt;
  const int end = min(beg + cnt, N);

  float dmin = FLT_MAX;
#pragma unroll 8
  for (int n = beg; n < end; ++n) {
    float4 q = P4[n];  // wave-uniform address -> broadcast load
    float t = fmaf(m2x, q.x, fmaf(m2y, q.y, fmaf(m2z, q.z, q.w)));
    dmin = fminf(dmin, t);
  }

  __shared__ float red[CHUNKS][64];
  red[wv][lane] = dmin;
  __syncthreads();

  if (wv == 0 && samp < M) {
    float d = red[0][lane];
#pragma unroll
    for (int w = 1; w < CHUNKS; ++w) d = fminf(d, red[w][lane]);
    const float s2 = __fadd_rn(
        __fadd_rn(__fmul_rn(sx, sx), __fmul_rn(sy, sy)), __fmul_rn(sz, sz));
    const float d2 = __fadd_rn(s2, d);
    const float dist = sqrtf(fmaxf(d2, 0.0f));
    const bool keep = dist > 1.0f;
    float* o = out + (size_t)(N + samp) * 3;
    o[0] = keep ? sx : 0.0f;
    o[1] = keep ? sy : 0.0f;
    o[2] = keep ? sz : 0.0f;
  }
}

extern "C" void kernel_launch(void* const* d_in, const int* in_sizes, int n_in,
                              void* d_out, int out_size, void* d_ws, size_t ws_size,
                              hipStream_t stream) {
  const float* p = (const float*)d_in[0];
  const float* u = (const float*)d_in[1];
  const int N = in_sizes[0] / 3;   // 8192
  const int M = in_sizes[1] / 3;   // 32768
  float* out = (float*)d_out;

  float* mmx = (float*)d_ws;                       // 6 floats
  float4* P4 = (float4*)((char*)d_ws + 256);       // N float4s

  const int copy_blocks = (N + 255) / 256;
  prep_kernel<<<dim3(1 + copy_blocks), 256, 0, stream>>>(p, N, out, P4, mmx);

  const int sblocks = (M + 63) / 64;
  dist_kernel<<<dim3(sblocks), dim3(64, CHUNKS), 0, stream>>>(u, M, N, P4, mmx, out);
}